// Round 5
// baseline (16220.784 us; speedup 1.0000x reference)
//
#include <hip/hip_runtime.h>
#include <hip/hip_fp16.h>
#include <math.h>

// Problem dims
#define T_STEPS 1024
#define BATCH   128
#define D_IN    256
#define H_DIM   256
#define NCOL    1024  // 4 gates * H
#define CH      16    // x-precompute chunk (steps)
#define NPER    8     // register-resident WH m-groups (k = 0..63)

typedef _Float16 half2_t __attribute__((ext_vector_type(2)));

__device__ __forceinline__ float sigmoidf_(float x) {
    return 1.0f / (1.0f + __expf(-x));
}

__device__ __forceinline__ float tanhf_(float x) {
    float ax = fabsf(x);
    float t = __expf(-2.0f * ax);
    float r = (1.0f - t) / (1.0f + t);
    return copysignf(r, x);
}

// 2-way f16 dot with f32 accumulate: acc += w.x*h.x + w.y*h.y
__device__ __forceinline__ float dot2f(unsigned int w, unsigned int h, float acc) {
#if __has_builtin(__builtin_amdgcn_fdot2)
    return __builtin_amdgcn_fdot2(__builtin_bit_cast(half2_t, w),
                                  __builtin_bit_cast(half2_t, h), acc, false);
#else
    __half2 wv = *(__half2*)&w, hv = *(__half2*)&h;
    acc = fmaf(__half2float(wv.x), __half2float(hv.x), acc);
    return fmaf(__half2float(wv.y), __half2float(hv.y), acc);
#endif
}

__device__ __forceinline__ unsigned int packh2(float a, float b) {
    __half2 p = __floats2half2_rn(a, b);
    return *(unsigned int*)&p;
}

__device__ __forceinline__ uint4 pack8(const float* p) {
    return make_uint4(packh2(p[0], p[1]), packh2(p[2], p[3]),
                      packh2(p[4], p[5]), packh2(p[6], p[7]));
}

// Layouts (j = gate*256 + h, m = 0..31 indexes k-octets):
//   WX4[m*1024 + j] = uint4 of f16 W[j][8m..8m+7]         (x part)
//   WH4[m*1024 + j] = uint4 of f16 W[j][256+8m..256+8m+7]  (hx part)
//   biasc[1024] fp32
__global__ __launch_bounds__(256) void prep_kernel(
    const float* __restrict__ Wf, const float* __restrict__ Wi,
    const float* __restrict__ Wg, const float* __restrict__ Wo,
    const float* __restrict__ bf, const float* __restrict__ bi,
    const float* __restrict__ bg, const float* __restrict__ bo,
    uint4* __restrict__ WX4, uint4* __restrict__ WH4,
    float* __restrict__ biasc)
{
    int idx = blockIdx.x * 256 + threadIdx.x;   // 0 .. 32767
    int m = idx >> 10;
    int j = idx & 1023;
    int g = j >> 8;
    int h = j & 255;
    const float* W = (g == 0) ? Wf : (g == 1) ? Wi : (g == 2) ? Wg : Wo;
    const float* row = W + h * (D_IN + H_DIM);
    WX4[idx] = pack8(row + 8 * m);
    WH4[idx] = pack8(row + D_IN + 8 * m);
    if (idx < NCOL) {
        const float* bb = (g == 0) ? bf : (g == 1) ? bi : (g == 2) ? bg : bo;
        biasc[idx] = bb[h];
    }
}

// 8 hi-dot2 + 8 lo-dot2 for one k-octet (m) against weight uint4 wv
#define DOT8(wv, mm)                                                        \
    do {                                                                    \
        uint4 hv_ = hh[mm], lv_ = hl[mm];                                   \
        aH = dot2f((wv).x, hv_.x, aH); aH = dot2f((wv).y, hv_.y, aH);       \
        aH = dot2f((wv).z, hv_.z, aH); aH = dot2f((wv).w, hv_.w, aH);       \
        aL = dot2f((wv).x, lv_.x, aL); aL = dot2f((wv).y, lv_.y, aL);       \
        aL = dot2f((wv).z, lv_.z, aL); aL = dot2f((wv).w, lv_.w, aL);       \
    } while (0)

// One block per batch row; 1024 threads (16 waves, 1 block/CU via VGPR>64).
// Thread tid owns column j = tid (j = gate*256 + h).
//  - chunk phase every CH steps: x-part preactivations in registers (f32 FMA,
//    wave-uniform x loads).
//  - steady step: WH low quarter register-resident, rest streamed with 2-deep
//    double-buffered prefetch issued before the LDS/dot phase.
//  - est layer 1 parallelized over all 16 waves (2 units each); layers 2-3
//    redundant per-thread on waves 0-3 (no escale barrier).
__global__ __launch_bounds__(1024, 4) void qlstm_kernel(
    const float* __restrict__ x,
    const uint4* __restrict__ WX4,
    const uint4* __restrict__ WH4,
    const float* __restrict__ biasc,
    const float* __restrict__ estW1, const float* __restrict__ estb1,
    const float* __restrict__ estW2, const float* __restrict__ estb2,
    const float* __restrict__ estW3, const float* __restrict__ estb3,
    float* __restrict__ out)
{
    __shared__ __align__(16) __half hxh[H_DIM];   // hi(hx)
    __shared__ __align__(16) __half hxl[H_DIM];   // lo(hx)
    __shared__ __align__(16) float gact[NCOL];    // activated gates
    __shared__ float w1[4 * 8 * H_DIM];  // estW1 permuted: [u][q*64+l] = h=4l+q
    __shared__ float sb1[32];
    __shared__ float sW2[128];
    __shared__ float sb2[16];
    __shared__ float sW3[16];
    __shared__ float sb3[4];
    __shared__ float sh1[32];            // est layer-1 outputs [gate*8+j]

    const int b    = blockIdx.x;
    const int tid  = threadIdx.x;
    const int w    = tid >> 6;
    const int lane = tid & 63;
    const int g_e  = w >> 2;             // est1: this wave's gate
    const int j0   = (w & 3) * 2;        // est1: this wave's first j

    // stage est params; permute w1 so lane-l float4 reads of gact are stride-1
    for (int i = tid; i < 4 * 8 * H_DIM; i += 1024) {
        int p = i & 255;
        int base = i & ~255;
        int h = 4 * (p & 63) + (p >> 6);
        w1[i] = estW1[base + h];
    }
    if (tid < 32)  sb1[tid] = estb1[tid];
    if (tid < 128) sW2[tid] = estW2[tid];
    if (tid < 16)  { sb2[tid] = estb2[tid]; sW3[tid] = estW3[tid]; }
    if (tid < 4)   sb3[tid] = estb3[tid];
    if (tid < H_DIM) {
        hxh[tid] = __float2half(0.0f);
        hxl[tid] = __float2half(0.0f);
    }
    float c_reg = 0.0f, h_reg = 0.0f;
    const float b_j = biasc[tid];
    __syncthreads();

    const uint4* hh = (const uint4*)hxh;   // 32 x (8 halves): k = 8m..8m+7
    const uint4* hl = (const uint4*)hxl;
    const uint4* wcol = WH4 + tid;

    // register-resident low quarter of the recurrent weights (never re-fetched)
    uint4 wper[NPER];
    #pragma unroll
    for (int m = 0; m < NPER; m++) wper[m] = wcol[m << 10];

    float pacc[CH];

    for (int t0 = 0; t0 < T_STEPS; t0 += CH) {
        // ---- chunk phase: pacc[s] = bias + Wx . x[t0+s], pure registers ----
        #pragma unroll
        for (int s = 0; s < CH; s++) pacc[s] = b_j;
        {
            const float* xb = x + ((size_t)t0 * BATCH + b) * D_IN;
            for (int m = 0; m < 32; m++) {
                uint4 wv = WX4[(m << 10) + tid];
                __half2 q0 = *(__half2*)&wv.x, q1 = *(__half2*)&wv.y;
                __half2 q2 = *(__half2*)&wv.z, q3 = *(__half2*)&wv.w;
                float w0 = __half2float(q0.x), w1f = __half2float(q0.y);
                float w2 = __half2float(q1.x), w3 = __half2float(q1.y);
                float w4 = __half2float(q2.x), w5 = __half2float(q2.y);
                float w6 = __half2float(q3.x), w7 = __half2float(q3.y);
                #pragma unroll
                for (int s = 0; s < CH; s++) {
                    const float* xr = xb + (size_t)s * (BATCH * D_IN) + (m << 3);
                    float4 xa = *(const float4*)xr;
                    float4 xc = *(const float4*)(xr + 4);
                    float a = pacc[s];
                    a = fmaf(w0, xa.x, a); a = fmaf(w1f, xa.y, a);
                    a = fmaf(w2, xa.z, a); a = fmaf(w3, xa.w, a);
                    a = fmaf(w4, xc.x, a); a = fmaf(w5, xc.y, a);
                    a = fmaf(w6, xc.z, a); a = fmaf(w7, xc.w, a);
                    pacc[s] = a;
                }
            }
        }

        // ---- CH recurrent steps consuming pacc ----
        #pragma unroll 1
        for (int s = 0; s < CH; s++) {
            const int t = t0 + s;
            // consume pacc[0]; shift (all static indices -> stays in VGPRs)
            float aH = pacc[0], aL = 0.0f;
            #pragma unroll
            for (int i = 0; i < CH - 1; i++) pacc[i] = pacc[i + 1];

            // issue first two stream groups before touching LDS (latency hide)
            uint4 sA[4], sB[4];
            #pragma unroll
            for (int i = 0; i < 4; i++) sA[i] = wcol[(NPER + i) << 10];
            #pragma unroll
            for (int i = 0; i < 4; i++) sB[i] = wcol[(NPER + 4 + i) << 10];

            // register-resident quarter: k = 0..63
            #pragma unroll
            for (int m = 0; m < NPER; m++) DOT8(wper[m], m);

            // streamed three quarters, 2-deep double buffer (m ascending)
            #pragma unroll
            for (int i = 0; i < 4; i++) DOT8(sA[i], 8 + i);
            #pragma unroll
            for (int i = 0; i < 4; i++) sA[i] = wcol[(16 + i) << 10];
            #pragma unroll
            for (int i = 0; i < 4; i++) DOT8(sB[i], 12 + i);
            #pragma unroll
            for (int i = 0; i < 4; i++) sB[i] = wcol[(20 + i) << 10];
            #pragma unroll
            for (int i = 0; i < 4; i++) DOT8(sA[i], 16 + i);
            #pragma unroll
            for (int i = 0; i < 4; i++) sA[i] = wcol[(24 + i) << 10];
            #pragma unroll
            for (int i = 0; i < 4; i++) DOT8(sB[i], 20 + i);
            #pragma unroll
            for (int i = 0; i < 4; i++) sB[i] = wcol[(28 + i) << 10];
            #pragma unroll
            for (int i = 0; i < 4; i++) DOT8(sA[i], 24 + i);
            #pragma unroll
            for (int i = 0; i < 4; i++) DOT8(sB[i], 28 + i);

            float acc = aH + aL;

            // activation: gate 2 (tid 512..767) tanh, others sigmoid
            float v = (tid >= 512 && tid < 768) ? tanhf_(acc) : sigmoidf_(acc);
            gact[tid] = v;
            __syncthreads();   // A: gates visible

            // est layer 1: 32 (gate,j) units over 16 waves, 2 per wave
            {
                float4 gv = ((const float4*)(gact + (g_e << 8)))[lane];
                #pragma unroll
                for (int jj = 0; jj < 2; jj++) {
                    const int u = g_e * 8 + j0 + jj;
                    const float* wr = &w1[u * H_DIM];
                    float s1 = fmaf(gv.x, wr[lane],
                               fmaf(gv.y, wr[lane + 64],
                               fmaf(gv.z, wr[lane + 128], gv.w * wr[lane + 192])));
                    #pragma unroll
                    for (int m2 = 1; m2 < 64; m2 <<= 1) s1 += __shfl_xor(s1, m2, 64);
                    if (lane == 0) sh1[u] = tanhf_(s1 + sb1[u]);
                }
            }
            __syncthreads();   // E: sh1 visible

            // est layers 2-3 (redundant per-thread) + state update: waves 0-3
            if (tid < 256) {
                float esc[4];
                #pragma unroll
                for (int g = 0; g < 4; g++) {
                    float h2[4];
                    #pragma unroll
                    for (int j = 0; j < 4; j++) {
                        float s2 = sb2[g * 4 + j];
                        #pragma unroll
                        for (int q = 0; q < 8; q++)
                            s2 = fmaf(sh1[g * 8 + q], sW2[g * 32 + j * 8 + q], s2);
                        h2[j] = tanhf_(s2);
                    }
                    float s3 = sb3[g];
                    #pragma unroll
                    for (int q = 0; q < 4; q++) s3 = fmaf(h2[q], sW3[g * 4 + q], s3);
                    esc[g] = sigmoidf_(s3);
                }
                float f  = gact[tid]       * esc[0];
                float ii = gact[256 + tid] * esc[1];
                float gg = gact[512 + tid] * esc[2];
                float o  = gact[768 + tid] * esc[3];
                c_reg = fmaf(f, c_reg, ii * gg);
                h_reg = o * tanhf_(c_reg);
                __half hi = __float2half_rn(h_reg);
                hxh[tid] = hi;
                hxl[tid] = __float2half_rn(h_reg - __half2float(hi));
                out[((size_t)t * BATCH + b) * H_DIM + tid] = h_reg;
            }
            __syncthreads();   // C: new hx visible to all waves
        }
    }

    if (tid < 256) {
        const size_t stacked = (size_t)T_STEPS * BATCH * H_DIM;
        out[stacked + (size_t)b * H_DIM + tid] = h_reg;
        out[stacked + (size_t)BATCH * H_DIM + (size_t)b * H_DIM + tid] = c_reg;
    }
}

extern "C" void kernel_launch(void* const* d_in, const int* in_sizes, int n_in,
                              void* d_out, int out_size, void* d_ws, size_t ws_size,
                              hipStream_t stream) {
    const float* x     = (const float*)d_in[0];
    const float* Wf    = (const float*)d_in[1];
    const float* bf    = (const float*)d_in[2];
    const float* Wi    = (const float*)d_in[3];
    const float* bi    = (const float*)d_in[4];
    const float* Wg    = (const float*)d_in[5];
    const float* bg    = (const float*)d_in[6];
    const float* Wo    = (const float*)d_in[7];
    const float* bo    = (const float*)d_in[8];
    const float* estW1 = (const float*)d_in[9];
    const float* estb1 = (const float*)d_in[10];
    const float* estW2 = (const float*)d_in[11];
    const float* estb2 = (const float*)d_in[12];
    const float* estW3 = (const float*)d_in[13];
    const float* estb3 = (const float*)d_in[14];

    uint4* WX4   = (uint4*)d_ws;                 // 32768 uint4 = 512 KB
    uint4* WH4   = WX4 + 32768;                  // 512 KB
    float* biasc = (float*)(WH4 + 32768);        // 4 KB

    prep_kernel<<<128, 256, 0, stream>>>(Wf, Wi, Wg, Wo, bf, bi, bg, bo,
                                         WX4, WH4, biasc);
    qlstm_kernel<<<BATCH, 1024, 0, stream>>>(
        x, WX4, WH4, biasc,
        estW1, estb1, estW2, estb2, estW3, estb3, (float*)d_out);
}